// Round 1
// baseline (2904.451 us; speedup 1.0000x reference)
//
#include <hip/hip_runtime.h>
#include <hip/hip_bf16.h>
#include <stdint.h>

typedef __hip_bfloat16 bf16;
typedef unsigned short u16;
typedef unsigned int u32;
typedef __bf16 v8bf __attribute__((ext_vector_type(8)));
typedef float v4f __attribute__((ext_vector_type(4)));

// Problem constants
#define NB 16384            // B
#define MROWS 147456        // T*B*3 token rows

__device__ __forceinline__ float b2f(u16 u) {
  union { u32 u; float f; } v; v.u = ((u32)u) << 16; return v.f;
}
__device__ __forceinline__ u16 f2b(float f) {
  union { float f; u32 u; } v; v.f = f;
  u32 u = v.u;
  return (u16)((u + 0x7fffu + ((u >> 16) & 1u)) >> 16);
}
__device__ __forceinline__ void async16(const u16* g, u16* lds) {
  __builtin_amdgcn_global_load_lds((const __attribute__((address_space(1))) void*)g,
                                   (__attribute__((address_space(3))) void*)lds,
                                   16, 0, 0);
}
__device__ __forceinline__ v4f mfma16(v8bf a, v8bf b, v4f c) {
  return __builtin_amdgcn_mfma_f32_16x16x32_bf16(a, b, c, 0, 0, 0);
}
// Swizzled LDS fragment reads. Tiles are row-major with XOR swizzle
// byte ^= (row&7)<<4 to break the 16-way bank conflict of D=256/D=128
// row-major tiles on ds_read_b128 (guide §6 G4).
__device__ __forceinline__ v8bf ldsA256(const u16* As, int row, int k) {
  int byte = (row << 9) + (k << 1);
  byte ^= (row & 7) << 4;
  return *(const v8bf*)((const char*)As + byte);
}
__device__ __forceinline__ v8bf ldsA128(const u16* As, int row, int k) {
  int byte = (row << 8) + (k << 1);
  byte ^= (row & 7) << 4;
  return *(const v8bf*)((const char*)As + byte);
}

// ---------------------------------------------------------------------------
// Weight prep (unchanged): transposed bf16 [N][K] per-layer layout in wt:
// q 0, k 65536, v 131072, o 196608, W1T 262144 (1024x256),
// W2T 524288 (256x1024); layer stride 786432 elements. bqkv: [l][qkv][256] f32.
// ---------------------------------------------------------------------------
__global__ __launch_bounds__(256)
void prep_weights(const float* Wq, const float* Wk, const float* Wv, const float* Wo,
                  const float* W1, const float* W2,
                  const float* bq, const float* bk, const float* bv,
                  bf16* wt, float* bqkv)
{
  if (blockIdx.x == 6144) {   // bias-pack block
    for (int e = threadIdx.x; e < 1536; e += 256) {
      int l = e / 768;
      int rem = e - l * 768;
      int wsel = rem >> 8;
      int col = rem & 255;
      const float* s = (wsel == 0) ? bq : (wsel == 1) ? bk : bv;
      bqkv[e] = s[l * 256 + col];
    }
    return;
  }
  int gid = blockIdx.x * 256 + threadIdx.x;   // [0, 1572864)
  int layer = (gid >= 786432) ? 1 : 0;
  int r = gid - layer * 786432;
  const float* src; int K, N, e, outoff;
  if (r < 262144) {
    int which = r >> 16;
    e = r & 65535; K = 256; N = 256;
    const float* w = (which == 0) ? Wq : (which == 1) ? Wk : (which == 2) ? Wv : Wo;
    src = w + layer * 65536;
    outoff = layer * 786432 + which * 65536;
  } else if (r < 524288) {
    e = r - 262144; K = 256; N = 1024;
    src = W1 + layer * 262144;
    outoff = layer * 786432 + 262144;
  } else {
    e = r - 524288; K = 1024; N = 256;
    src = W2 + layer * 262144;
    outoff = layer * 786432 + 524288;
  }
  int n = e / K, kk = e - n * K;
  ((u16*)wt)[outoff + e] = f2b(src[kk * N + n]);
}

// ---------------------------------------------------------------------------
// Graph-message build: write x rows (f32). 1 wave per row, 4 rows per block.
// (LN is now fused into qkv_fused, so no h output here.)
// ---------------------------------------------------------------------------
__global__ __launch_bounds__(256)
void build_x(const float* __restrict__ T, const float* __restrict__ P,
             float* __restrict__ X, int row0)
{
  const int lane = threadIdx.x & 63;
  const int lrow = blockIdx.x * 4 + (threadIdx.x >> 6);
  const int row = row0 + lrow;
  const int d0 = lane * 4;
  int n = row / 3;
  int t = row - n * 3;
  float4 v;
  if (t == 2) {
    v = *(const float4*)(T + (size_t)n * 256 + d0);
  } else {
    int tm = n >> 14, b = n & 16383;
    const int srcT[6] = {1, 2,  0, 2,  1, 0};
    const int srcP[6] = {0, 2,  0, 1,  1, 2};
    const float sg[6] = {-1.f, -1.f,  1.f, -1.f,  1.f, 1.f};
    int idx = tm * 2 + t;
    float4 tv = *(const float4*)(T + ((size_t)(srcT[idx] * NB + b)) * 256 + d0);
    float4 pv = *(const float4*)(P + ((size_t)(srcP[idx] * NB + b)) * 256 + d0);
    float s = sg[idx];
    v.x = tv.x + s * pv.x;
    v.y = tv.y + s * pv.y;
    v.z = tv.z + s * pv.z;
    v.w = tv.w + s * pv.w;
  }
  *(float4*)(X + (size_t)lrow * 256 + d0) = v;
}

// ---------------------------------------------------------------------------
// LN stage: read 64 rows of x (f32), LayerNorm, write bf16 into swizzled LDS
// tile As[64][256]. Wave w handles rows {w, w+8, ..., w+56}; each row read is
// a fully-coalesced 1 KB wave read + 64-lane shfl reduction.
// ---------------------------------------------------------------------------
__device__ __forceinline__ void ln_stage(const float* __restrict__ xp,
                                         const float* __restrict__ gp,
                                         const float* __restrict__ bp,
                                         u16* As, int m0, int w, int lane)
{
  const float4 gv = *(const float4*)(gp + lane * 4);
  const float4 bv = *(const float4*)(bp + lane * 4);
  for (int r = w; r < 64; r += 8) {
    float4 v = *(const float4*)(xp + (size_t)(m0 + r) * 256 + lane * 4);
    float s = v.x + v.y + v.z + v.w;
    float q = v.x * v.x + v.y * v.y + v.z * v.z + v.w * v.w;
    #pragma unroll
    for (int m = 32; m > 0; m >>= 1) {
      s += __shfl_xor(s, m, 64);
      q += __shfl_xor(q, m, 64);
    }
    float mean = s * (1.f / 256.f);
    float var = q * (1.f / 256.f) - mean * mean;
    float rr = rsqrtf(var + 1e-5f);
    ushort4 o;
    o.x = f2b((v.x - mean) * rr * gv.x + bv.x);
    o.y = f2b((v.y - mean) * rr * gv.y + bv.y);
    o.z = f2b((v.z - mean) * rr * gv.z + bv.z);
    o.w = f2b((v.w - mean) * rr * gv.w + bv.w);
    int byte = (r << 9) + (lane << 3);
    byte ^= (r & 7) << 4;
    *(ushort4*)((char*)As + byte) = o;
  }
}

// ---------------------------------------------------------------------------
// Fused LN1 + QKV projection. One 64-row tile per block, 512 threads (8 waves,
// 2m x 4n). A (LN'd x) staged ONCE in swizzled LDS; the six 128-col output
// blocks (q0,q1,k0,k1,v0,v1) loop inside so A is never re-fetched from HBM.
// Weight B-fragments are read directly from global (L2-resident, 384 KB).
// One barrier total.
// ---------------------------------------------------------------------------
__global__ __launch_bounds__(512, 4)
void qkv_fused(const float* __restrict__ xp, const float* __restrict__ gp,
               const float* __restrict__ bp, const bf16* __restrict__ wp,
               const float* __restrict__ biasp, bf16* __restrict__ qkv,
               long long qkvZ)
{
  __shared__ __align__(16) u16 As[64 * 256];
  const int tid = threadIdx.x;
  const int w = tid >> 6, lane = tid & 63;
  const int m0 = blockIdx.x * 64;
  ln_stage(xp, gp, bp, As, m0, w, lane);
  __syncthreads();
  const int wr = (w >> 2) * 32;
  const int wc = (w & 3) * 32;
  const int fl = lane & 15, fh = lane >> 4;
  #pragma unroll 1
  for (int nb = 0; nb < 6; nb++) {
    const int wsel = nb >> 1, c0 = (nb & 1) * 128;
    const u16* B = (const u16*)wp + wsel * 65536 + (size_t)(c0 + wc) * 256;
    v4f acc[2][2];
    #pragma unroll
    for (int i = 0; i < 2; i++)
      #pragma unroll
      for (int j = 0; j < 2; j++) {
        v4f z = {0.f, 0.f, 0.f, 0.f};
        acc[i][j] = z;
      }
    #pragma unroll
    for (int kk = 0; kk < 8; kk++) {
      const int k0 = kk * 32 + fh * 8;
      v8bf a0 = ldsA256(As, wr + fl, k0);
      v8bf a1 = ldsA256(As, wr + 16 + fl, k0);
      v8bf b0 = *(const v8bf*)(B + (size_t)fl * 256 + k0);
      v8bf b1 = *(const v8bf*)(B + (size_t)(16 + fl) * 256 + k0);
      acc[0][0] = mfma16(a0, b0, acc[0][0]);
      acc[1][0] = mfma16(a1, b0, acc[1][0]);
      acc[0][1] = mfma16(a0, b1, acc[0][1]);
      acc[1][1] = mfma16(a1, b1, acc[1][1]);
    }
    u16* out = (u16*)qkv + (size_t)wsel * qkvZ;
    #pragma unroll
    for (int nj = 0; nj < 2; nj++) {
      const int col = c0 + wc + nj * 16 + fl;
      const float bb = biasp[wsel * 256 + col];
      #pragma unroll
      for (int mi = 0; mi < 2; mi++)
        #pragma unroll
        for (int r2 = 0; r2 < 4; r2++) {
          int row = m0 + wr + mi * 16 + fh * 4 + r2;
          out[(size_t)row * 256 + col] = f2b(acc[mi][nj][r2] + bb);
        }
    }
  }
}

// ---------------------------------------------------------------------------
// O-projection: x += o @ WoT + bo. A (o tile) staged via global_load_lds with
// PRE-SWIZZLED SOURCE addresses (linear LDS dest, XOR'd global 16B slot), so
// the swizzled ds_read_b128 fragment reads are conflict-free. Full 64x256 C
// per block across 8 waves; Wo b-frags direct from global. One barrier.
// ---------------------------------------------------------------------------
__global__ __launch_bounds__(512, 4)
void oproj(const bf16* __restrict__ op, const bf16* __restrict__ wop,
           const float* __restrict__ bop, float* __restrict__ xp)
{
  __shared__ __align__(16) u16 As[64 * 256];
  const int tid = threadIdx.x;
  const int w = tid >> 6, lane = tid & 63;
  const int m0 = blockIdx.x * 64;
  const u16* og = (const u16*)op + (size_t)m0 * 256;
  #pragma unroll
  for (int i = 0; i < 4; i++) {
    int b = i * 8192 + tid * 16;                 // linear LDS byte
    int row = b >> 9, cb = b & 511;
    int srfranja = (row << 8) + ((cb ^ ((row & 7) << 4)) >> 1);  // u16 elems
    async16(og + srfranja, As + (b >> 1));
  }
  __syncthreads();
  const int wr = (w >> 2) * 32;
  const int wc = (w & 3) * 64;
  const int fl = lane & 15, fh = lane >> 4;
  v4f acc[2][4];
  #pragma unroll
  for (int i = 0; i < 2; i++)
    #pragma unroll
    for (int j = 0; j < 4; j++) {
      v4f z = {0.f, 0.f, 0.f, 0.f};
      acc[i][j] = z;
    }
  #pragma unroll
  for (int kk = 0; kk < 8; kk++) {
    const int k0 = kk * 32 + fh * 8;
    v8bf a0 = ldsA256(As, wr + fl, k0);
    v8bf a1 = ldsA256(As, wr + 16 + fl, k0);
    #pragma unroll
    for (int nj = 0; nj < 4; nj++) {
      v8bf b = *(const v8bf*)((const u16*)wop + (size_t)(wc + nj * 16 + fl) * 256 + k0);
      acc[0][nj] = mfma16(a0, b, acc[0][nj]);
      acc[1][nj] = mfma16(a1, b, acc[1][nj]);
    }
  }
  #pragma unroll
  for (int nj = 0; nj < 4; nj++) {
    const int col = wc + nj * 16 + fl;
    const float bb = bop[col];
    #pragma unroll
    for (int mi = 0; mi < 2; mi++)
      #pragma unroll
      for (int r2 = 0; r2 < 4; r2++) {
        size_t idx = (size_t)(m0 + wr + mi * 16 + fh * 4 + r2) * 256 + col;
        xp[idx] += acc[mi][nj][r2] + bb;
      }
  }
}

// ---------------------------------------------------------------------------
// Fused FFN: x += relu(LN2(x) @ W1 + b1) @ W2 + b2.  One 64-row tile per
// block, 512 threads. LN'd A staged once (32 KB swizzled LDS). For each of 8
// 128-col chunks of the hidden: compute f-chunk in registers (W1 MFMAs, A from
// LDS, W1T b-frags direct global), bias+relu, round-trip through a 16 KB
// swizzled LDS buffer (fragment-layout transpose), then accumulate the W2
// product into the persistent 64x256 C accumulator. The 1024-wide hidden
// NEVER touches HBM; A is fetched exactly once. 2 barriers per chunk.
// ---------------------------------------------------------------------------
__global__ __launch_bounds__(512, 4)
void ffn_fused(float* __restrict__ xp, const float* __restrict__ gp,
               const float* __restrict__ bp, const bf16* __restrict__ w1p,
               const bf16* __restrict__ w2p, const float* __restrict__ b1p,
               const float* __restrict__ b2p)
{
  __shared__ __align__(16) u16 As[64 * 256];   // 32 KB
  __shared__ __align__(16) u16 Fs[64 * 128];   // 16 KB
  const int tid = threadIdx.x;
  const int w = tid >> 6, lane = tid & 63;
  const int m0 = blockIdx.x * 64;
  ln_stage(xp, gp, bp, As, m0, w, lane);
  __syncthreads();
  const int wr = (w >> 2) * 32;
  const int wc = (w & 3);
  const int fl = lane & 15, fh = lane >> 4;
  v4f acc[2][4];
  #pragma unroll
  for (int i = 0; i < 2; i++)
    #pragma unroll
    for (int j = 0; j < 4; j++) {
      v4f z = {0.f, 0.f, 0.f, 0.f};
      acc[i][j] = z;
    }
  #pragma unroll 1
  for (int nc = 0; nc < 8; nc++) {
    // ---- W1 phase: f-chunk 64x128, per-wave 32x32 ----
    v4f fa[2][2];
    #pragma unroll
    for (int i = 0; i < 2; i++)
      #pragma unroll
      for (int j = 0; j < 2; j++) {
        v4f z = {0.f, 0.f, 0.f, 0.f};
        fa[i][j] = z;
      }
    const u16* B1 = (const u16*)w1p + (size_t)(nc * 128 + wc * 32) * 256;
    #pragma unroll
    for (int kk = 0; kk < 8; kk++) {
      const int k0 = kk * 32 + fh * 8;
      v8bf a0 = ldsA256(As, wr + fl, k0);
      v8bf a1 = ldsA256(As, wr + 16 + fl, k0);
      v8bf b0 = *(const v8bf*)(B1 + (size_t)fl * 256 + k0);
      v8bf b1 = *(const v8bf*)(B1 + (size_t)(16 + fl) * 256 + k0);
      fa[0][0] = mfma16(a0, b0, fa[0][0]);
      fa[1][0] = mfma16(a1, b0, fa[1][0]);
      fa[0][1] = mfma16(a0, b1, fa[0][1]);
      fa[1][1] = mfma16(a1, b1, fa[1][1]);
    }
    // bias + relu -> swizzled Fs
    #pragma unroll
    for (int nj = 0; nj < 2; nj++) {
      const int colc = wc * 32 + nj * 16 + fl;     // 0..127 within chunk
      const float bb = b1p[nc * 128 + colc];
      #pragma unroll
      for (int mi = 0; mi < 2; mi++)
        #pragma unroll
        for (int r2 = 0; r2 < 4; r2++) {
          int row = wr + mi * 16 + fh * 4 + r2;
          float vv = fmaxf(fa[mi][nj][r2] + bb, 0.f);
          int byte = (row << 8) + (colc << 1);
          byte ^= (row & 7) << 4;
          *(u16*)((char*)Fs + byte) = f2b(vv);
        }
    }
    __syncthreads();     // Fs chunk complete
    // ---- W2 phase: C += f_chunk @ W2T[:, nc*128 .. +128] ----
    #pragma unroll
    for (int kk = 0; kk < 4; kk++) {
      const int k0 = kk * 32 + fh * 8;             // within-chunk k
      v8bf a0 = ldsA128(Fs, wr + fl, k0);
      v8bf a1 = ldsA128(Fs, wr + 16 + fl, k0);
      #pragma unroll
      for (int nj = 0; nj < 4; nj++) {
        v8bf b = *(const v8bf*)((const u16*)w2p +
                                (size_t)((w & 3) * 64 + nj * 16 + fl) * 1024 +
                                nc * 128 + k0);
        acc[0][nj] = mfma16(a0, b, acc[0][nj]);
        acc[1][nj] = mfma16(a1, b, acc[1][nj]);
      }
    }
    __syncthreads();     // all reads done before next chunk overwrites Fs
  }
  // epilogue: + b2 + residual, write x (f32)
  #pragma unroll
  for (int nj = 0; nj < 4; nj++) {
    const int col = (w & 3) * 64 + nj * 16 + fl;
    const float bb = b2p[col];
    #pragma unroll
    for (int mi = 0; mi < 2; mi++)
      #pragma unroll
      for (int r2 = 0; r2 < 4; r2++) {
        size_t idx = (size_t)(m0 + wr + mi * 16 + fh * 4 + r2) * 256 + col;
        xp[idx] += acc[mi][nj][r2] + bb;
      }
  }
}

// ---------------------------------------------------------------------------
// Attention: seq_len 3, H=8, DH=32, bf16 in/out. 8 sequences per block.
// ---------------------------------------------------------------------------
__global__ __launch_bounds__(256)
void attn(const bf16* __restrict__ qp, const bf16* __restrict__ kp,
          const bf16* __restrict__ vp, bf16* __restrict__ op)
{
  __shared__ __align__(16) u16 qs[6144], ks[6144], vs[6144];
  __shared__ float probs[8][8][9];
  const int tid = threadIdx.x;
  const size_t gbase = (size_t)blockIdx.x * 6144;   // 8 seq * 3 tok * 256
  const uint4* qg = (const uint4*)((const u16*)qp + gbase);
  const uint4* kg = (const uint4*)((const u16*)kp + gbase);
  const uint4* vg = (const uint4*)((const u16*)vp + gbase);
  for (int c = tid; c < 768; c += 256) {
    ((uint4*)qs)[c] = qg[c];
    ((uint4*)ks)[c] = kg[c];
    ((uint4*)vs)[c] = vg[c];
  }
  __syncthreads();
  if (tid < 64) {
    int s = tid >> 3, h = tid & 7;
    int base = s * 768 + h * 32;
    float sc[3][3];
    #pragma unroll
    for (int i = 0; i < 3; i++)
      #pragma unroll
      for (int j = 0; j < 3; j++) {
        float sum = 0.f;
        #pragma unroll
        for (int d = 0; d < 32; d++)
          sum += b2f(qs[base + i * 256 + d]) * b2f(ks[base + j * 256 + d]);
        sc[i][j] = sum * 0.17677669529663687f;   // DH^-0.5
      }
    #pragma unroll
    for (int i = 0; i < 3; i++) {
      float m = fmaxf(sc[i][0], fmaxf(sc[i][1], sc[i][2]));
      float e0 = __expf(sc[i][0] - m);
      float e1 = __expf(sc[i][1] - m);
      float e2 = __expf(sc[i][2] - m);
      float inv = 1.f / (e0 + e1 + e2);
      probs[s][h][i * 3 + 0] = e0 * inv;
      probs[s][h][i * 3 + 1] = e1 * inv;
      probs[s][h][i * 3 + 2] = e2 * inv;
    }
  }
  __syncthreads();
  u16* og = (u16*)op + gbase;
  for (int c = tid; c < 6144; c += 256) {
    int lrow = c >> 8, hd = c & 255;
    int s = lrow / 3, i = lrow - s * 3;
    int h = hd >> 5;
    float p0 = probs[s][h][i * 3 + 0];
    float p1 = probs[s][h][i * 3 + 1];
    float p2 = probs[s][h][i * 3 + 2];
    float o = p0 * b2f(vs[s * 768 + hd])
            + p1 * b2f(vs[s * 768 + 256 + hd])
            + p2 * b2f(vs[s * 768 + 512 + hd]);
    og[c] = f2b(o);
  }
}

// ---------------------------------------------------------------------------
// Final LN + mean over 3 tokens (f32 in, f32 out). 1 wave/seq, 4 seq/block.
// ---------------------------------------------------------------------------
__global__ __launch_bounds__(256)
void ln_final_mean(const float* __restrict__ xp, const float* __restrict__ gp,
                   const float* __restrict__ bp, float* __restrict__ outp)
{
  const int lane = threadIdx.x & 63;
  const int n = blockIdx.x * 4 + (threadIdx.x >> 6);
  float4 gv = *(const float4*)(gp + lane * 4);
  float4 bv4 = *(const float4*)(bp + lane * 4);
  float a0 = 0.f, a1 = 0.f, a2 = 0.f, a3 = 0.f;
  for (int t = 0; t < 3; t++) {
    float4 rv = *(const float4*)(xp + ((size_t)n * 3 + t) * 256 + lane * 4);
    float v0 = rv.x, v1 = rv.y, v2 = rv.z, v3 = rv.w;
    float s = v0 + v1 + v2 + v3;
    float q = v0 * v0 + v1 * v1 + v2 * v2 + v3 * v3;
    #pragma unroll
    for (int m = 32; m > 0; m >>= 1) {
      s += __shfl_xor(s, m, 64);
      q += __shfl_xor(q, m, 64);
    }
    float mean = s * (1.f / 256.f);
    float var = q * (1.f / 256.f) - mean * mean;
    float r = rsqrtf(var + 1e-5f);
    a0 += (v0 - mean) * r * gv.x + bv4.x;
    a1 += (v1 - mean) * r * gv.y + bv4.y;
    a2 += (v2 - mean) * r * gv.z + bv4.z;
    a3 += (v3 - mean) * r * gv.w + bv4.w;
  }
  const float third = 1.f / 3.f;
  float4 outv;
  outv.x = a0 * third;
  outv.y = a1 * third;
  outv.z = a2 * third;
  outv.w = a3 * third;
  *(float4*)(outp + (size_t)n * 256 + lane * 4) = outv;
}

// ---------------------------------------------------------------------------
extern "C" void kernel_launch(void* const* d_in, const int* in_sizes, int n_in,
                              void* d_out, int out_size, void* d_ws, size_t ws_size,
                              hipStream_t stream)
{
  const float* term = (const float*)d_in[0];
  const float* pred = (const float*)d_in[1];
  const float* Wq  = (const float*)d_in[2];
  const float* Wk  = (const float*)d_in[3];
  const float* Wv  = (const float*)d_in[4];
  const float* Wo  = (const float*)d_in[5];
  const float* bq  = (const float*)d_in[6];
  const float* bk  = (const float*)d_in[7];
  const float* bvv = (const float*)d_in[8];
  const float* bo  = (const float*)d_in[9];
  const float* ln1g = (const float*)d_in[10];
  const float* ln1b = (const float*)d_in[11];
  const float* ln2g = (const float*)d_in[12];
  const float* ln2b = (const float*)d_in[13];
  const float* W1  = (const float*)d_in[14];
  const float* b1  = (const float*)d_in[15];
  const float* W2  = (const float*)d_in[16];
  const float* b2  = (const float*)d_in[17];
  const float* lnfg = (const float*)d_in[18];
  const float* lnfb = (const float*)d_in[19];

  // Chunk count from ws_size. Per row: x f32 (1024 B) + q,k,v,o bf16 (2048 B).
  // (h and f eliminated by fusion.) Start at nch=4 so the per-chunk working
  // set (~132 MB) stays L3-resident.
  int nch = 128;
  for (int c = 4; c <= 128; c *= 2) {
    size_t Mc_ = (size_t)MROWS / c;
    size_t need = 4ull * 1024 * 1024 + Mc_ * 3072ull;
    if (need <= ws_size) { nch = c; break; }
  }
  const size_t Mc = (size_t)MROWS / nch;     // multiple of 1152

  char* ws = (char*)d_ws;
  bf16* wt   = (bf16*)ws;                    // 1572864 el (3 MB)
  float* bqkv = (float*)(ws + 3145728);      // 1536 f32
  float* x = (float*)(ws + 4194304);         // Mc*256 f32
  bf16* q = (bf16*)(x + Mc * 256);           // q,k,v,o contiguous bf16
  bf16* v_ = q + 2 * Mc * 256;
  bf16* o = q + 3 * Mc * 256;

  prep_weights<<<6145, 256, 0, stream>>>(Wq, Wk, Wv, Wo, W1, W2, bq, bk, bvv, wt, bqkv);

  const long long qkvZ = (long long)(Mc * 256);
  for (int ch = 0; ch < nch; ch++) {
    const int row0 = (int)(ch * Mc);
    build_x<<<(int)(Mc / 4), 256, 0, stream>>>(term, pred, x, row0);
    for (int l = 0; l < 2; l++) {
      const bf16* wl = wt + (size_t)l * 786432;
      qkv_fused<<<(int)(Mc / 64), 512, 0, stream>>>(
          x, ln1g + l * 256, ln1b + l * 256, wl, bqkv + l * 768, q, qkvZ);
      attn<<<(int)(Mc / 24), 256, 0, stream>>>(q, q + Mc * 256, v_, o);
      oproj<<<(int)(Mc / 64), 512, 0, stream>>>(o, wl + 196608, bo + l * 256, x);
      ffn_fused<<<(int)(Mc / 64), 512, 0, stream>>>(
          x, ln2g + l * 256, ln2b + l * 256, wl + 262144, wl + 524288,
          b1 + l * 1024, b2 + l * 256);
    }
    ln_final_mean<<<(int)(Mc / 12), 256, 0, stream>>>(
        x, lnfg, lnfb, (float*)d_out + (size_t)(row0 / 3) * 256);
  }
}

// Round 2
// 1551.020 us; speedup vs baseline: 1.8726x; 1.8726x over previous
//
#include <hip/hip_runtime.h>
#include <hip/hip_bf16.h>
#include <stdint.h>

typedef __hip_bfloat16 bf16;
typedef unsigned short u16;
typedef unsigned int u32;
typedef __bf16 v8bf __attribute__((ext_vector_type(8)));
typedef float v4f __attribute__((ext_vector_type(4)));

// Problem constants
#define NB 16384            // B
#define MROWS 147456        // T*B*3 token rows

__device__ __forceinline__ float b2f(u16 u) {
  union { u32 u; float f; } v; v.u = ((u32)u) << 16; return v.f;
}
__device__ __forceinline__ u16 f2b(float f) {
  union { float f; u32 u; } v; v.f = f;
  u32 u = v.u;
  return (u16)((u + 0x7fffu + ((u >> 16) & 1u)) >> 16);
}
__device__ __forceinline__ void async16(const u16* g, u16* lds) {
  __builtin_amdgcn_global_load_lds((const __attribute__((address_space(1))) void*)g,
                                   (__attribute__((address_space(3))) void*)lds,
                                   16, 0, 0);
}
__device__ __forceinline__ v4f mfma16(v8bf a, v8bf b, v4f c) {
  return __builtin_amdgcn_mfma_f32_16x16x32_bf16(a, b, c, 0, 0, 0);
}

// ---- swizzled LDS reads -----------------------------------------------------
// As: [rows][256] bf16 (512 B rows), XOR (row&7)<<4  -> conflict-free b128 frags
__device__ __forceinline__ v8bf ldsA256(const u16* As, int row, int k) {
  int byte = (row << 9) + ((k << 1) ^ ((row & 7) << 4));
  return *(const v8bf*)((const char*)As + byte);
}
// Fs: [rows][128] bf16 (256 B rows), XOR (row&7)<<4
__device__ __forceinline__ v8bf ldsA128(const u16* As, int row, int k) {
  int byte = (row << 8) + ((k << 1) ^ ((row & 7) << 4));
  return *(const v8bf*)((const char*)As + byte);
}
// B tile [128 rows][64 k] (128 B rows), XOR (row&7)<<4; kb = in-row byte
__device__ __forceinline__ v8bf ldsB64(const u16* Bs, int row, int kb) {
  int byte = (row << 7) + (kb ^ ((row & 7) << 4));
  return *(const v8bf*)((const char*)Bs + byte);
}
// B tile [256 rows][32 k] (64 B rows), XOR ((row>>1)&3)<<4
__device__ __forceinline__ v8bf ldsB32(const u16* Bs, int row, int kb) {
  int byte = (row << 6) + (kb ^ (((row >> 1) & 3) << 4));
  return *(const v8bf*)((const char*)Bs + byte);
}

// ---- B-tile staging via global_load_lds (linear LDS dest, pre-swizzled src).
// Per-thread constant source offsets; 2x async16 per thread per 16 KB tile.
// [128][64] tile, global row stride 256 elems:
__device__ __forceinline__ void so_128x64(int tid, int* so) {
  #pragma unroll
  for (int i = 0; i < 2; i++) {
    int b = (tid + i * 512) * 16;
    int r = b >> 7, ib = b & 127;
    so[i] = r * 256 + ((ib ^ ((r & 7) << 4)) >> 1);
  }
}
// [256][32] tile, global row stride S elems:
__device__ __forceinline__ void so_256x32(int tid, int S, int* so) {
  #pragma unroll
  for (int i = 0; i < 2; i++) {
    int b = (tid + i * 512) * 16;
    int r = b >> 6, ib = b & 63;
    so[i] = r * S + ((ib ^ (((r >> 1) & 3) << 4)) >> 1);
  }
}
__device__ __forceinline__ void stage_tile(const u16* g, const int* so, u16* Bs,
                                           int bufo, int tid) {
  async16(g + so[0], Bs + bufo + tid * 8);
  async16(g + so[1], Bs + bufo + tid * 8 + 4096);
}

// ---------------------------------------------------------------------------
// Weight prep (unchanged): transposed bf16 [N][K] per-layer layout in wt:
// q 0, k 65536, v 131072, o 196608, W1T 262144 (1024x256),
// W2T 524288 (256x1024); layer stride 786432 elements. bqkv: [l][qkv][256] f32.
// ---------------------------------------------------------------------------
__global__ __launch_bounds__(256)
void prep_weights(const float* Wq, const float* Wk, const float* Wv, const float* Wo,
                  const float* W1, const float* W2,
                  const float* bq, const float* bk, const float* bv,
                  bf16* wt, float* bqkv)
{
  if (blockIdx.x == 6144) {   // bias-pack block
    for (int e = threadIdx.x; e < 1536; e += 256) {
      int l = e / 768;
      int rem = e - l * 768;
      int wsel = rem >> 8;
      int col = rem & 255;
      const float* s = (wsel == 0) ? bq : (wsel == 1) ? bk : bv;
      bqkv[e] = s[l * 256 + col];
    }
    return;
  }
  int gid = blockIdx.x * 256 + threadIdx.x;   // [0, 1572864)
  int layer = (gid >= 786432) ? 1 : 0;
  int r = gid - layer * 786432;
  const float* src; int K, N, e, outoff;
  if (r < 262144) {
    int which = r >> 16;
    e = r & 65535; K = 256; N = 256;
    const float* w = (which == 0) ? Wq : (which == 1) ? Wk : (which == 2) ? Wv : Wo;
    src = w + layer * 65536;
    outoff = layer * 786432 + which * 65536;
  } else if (r < 524288) {
    e = r - 262144; K = 256; N = 1024;
    src = W1 + layer * 262144;
    outoff = layer * 786432 + 262144;
  } else {
    e = r - 524288; K = 1024; N = 256;
    src = W2 + layer * 262144;
    outoff = layer * 786432 + 524288;
  }
  int n = e / K, kk = e - n * K;
  ((u16*)wt)[outoff + e] = f2b(src[kk * N + n]);
}

// ---------------------------------------------------------------------------
// Graph-message build: write x rows (f32). 1 wave per row, 4 rows per block.
// ---------------------------------------------------------------------------
__global__ __launch_bounds__(256)
void build_x(const float* __restrict__ T, const float* __restrict__ P,
             float* __restrict__ X, int row0)
{
  const int lane = threadIdx.x & 63;
  const int lrow = blockIdx.x * 4 + (threadIdx.x >> 6);
  const int row = row0 + lrow;
  const int d0 = lane * 4;
  int n = row / 3;
  int t = row - n * 3;
  float4 v;
  if (t == 2) {
    v = *(const float4*)(T + (size_t)n * 256 + d0);
  } else {
    int tm = n >> 14, b = n & 16383;
    const int srcT[6] = {1, 2,  0, 2,  1, 0};
    const int srcP[6] = {0, 2,  0, 1,  1, 2};
    const float sg[6] = {-1.f, -1.f,  1.f, -1.f,  1.f, 1.f};
    int idx = tm * 2 + t;
    float4 tv = *(const float4*)(T + ((size_t)(srcT[idx] * NB + b)) * 256 + d0);
    float4 pv = *(const float4*)(P + ((size_t)(srcP[idx] * NB + b)) * 256 + d0);
    float s = sg[idx];
    v.x = tv.x + s * pv.x;
    v.y = tv.y + s * pv.y;
    v.z = tv.z + s * pv.z;
    v.w = tv.w + s * pv.w;
  }
  *(float4*)(X + (size_t)lrow * 256 + d0) = v;
}

// ---------------------------------------------------------------------------
// LN stage: read 64 rows of x (f32), LayerNorm, write bf16 into swizzled LDS
// tile As[64][256]. Wave w handles rows {w, w+8, ..., w+56}.
// ---------------------------------------------------------------------------
__device__ __forceinline__ void ln_stage(const float* __restrict__ xp,
                                         const float* __restrict__ gp,
                                         const float* __restrict__ bp,
                                         u16* As, int m0, int w, int lane)
{
  const float4 gv = *(const float4*)(gp + lane * 4);
  const float4 bv = *(const float4*)(bp + lane * 4);
  for (int r = w; r < 64; r += 8) {
    float4 v = *(const float4*)(xp + (size_t)(m0 + r) * 256 + lane * 4);
    float s = v.x + v.y + v.z + v.w;
    float q = v.x * v.x + v.y * v.y + v.z * v.z + v.w * v.w;
    #pragma unroll
    for (int m = 32; m > 0; m >>= 1) {
      s += __shfl_xor(s, m, 64);
      q += __shfl_xor(q, m, 64);
    }
    float mean = s * (1.f / 256.f);
    float var = q * (1.f / 256.f) - mean * mean;
    float rr = rsqrtf(var + 1e-5f);
    ushort4 o;
    o.x = f2b((v.x - mean) * rr * gv.x + bv.x);
    o.y = f2b((v.y - mean) * rr * gv.y + bv.y);
    o.z = f2b((v.z - mean) * rr * gv.z + bv.z);
    o.w = f2b((v.w - mean) * rr * gv.w + bv.w);
    int byte = (r << 9) + ((lane << 3) ^ ((r & 7) << 4));
    *(ushort4*)((char*)As + byte) = o;
  }
}

// ---------------------------------------------------------------------------
// Fused LN1 + QKV projection. 64-row tile, 8 waves (2m x 4n). A staged once in
// swizzled LDS; B (q,k,v weights) pipelined through a 32 KB double buffer via
// global_load_lds: 24 tiles of [128 cols][64 k]. 8 MFMA/wave per barrier step.
// ---------------------------------------------------------------------------
__global__ __launch_bounds__(512, 4)
void qkv_fused(const float* __restrict__ xp, const float* __restrict__ gp,
               const float* __restrict__ bp, const bf16* __restrict__ wp,
               const float* __restrict__ biasp, bf16* __restrict__ qkv,
               long long qkvZ)
{
  __shared__ __align__(16) u16 As[64 * 256];   // 32 KB
  __shared__ __align__(16) u16 Bs[2 * 8192];   // 32 KB
  const int tid = threadIdx.x;
  const int w = tid >> 6, lane = tid & 63;
  const int m0 = blockIdx.x * 64;
  int so[2];
  so_128x64(tid, so);
  const u16* wp16 = (const u16*)wp;
  // preload tile 0 (nb=0 -> wsel 0, c0 0; ks=0)
  stage_tile(wp16, so, Bs, 0, tid);
  ln_stage(xp, gp, bp, As, m0, w, lane);
  const int wr = (w >> 2) * 32;
  const int wc = (w & 3) * 32;
  const int fl = lane & 15, fh = lane >> 4;
  v4f acc[2][2];
  #pragma unroll
  for (int i = 0; i < 2; i++)
    #pragma unroll
    for (int j = 0; j < 2; j++) { v4f z = {0.f,0.f,0.f,0.f}; acc[i][j] = z; }
  #pragma unroll 1
  for (int t = 0; t < 24; t++) {
    __syncthreads();
    if (t + 1 < 24) {
      int t1 = t + 1, nb1 = t1 >> 2, ks1 = t1 & 3;
      const u16* g = wp16 + (nb1 >> 1) * 65536 + ((nb1 & 1) * 128) * 256 + ks1 * 64;
      stage_tile(g, so, Bs, ((t + 1) & 1) * 8192, tid);
    }
    const u16* Bt = Bs + (t & 1) * 8192;
    const int ks = t & 3;
    #pragma unroll
    for (int kl = 0; kl < 2; kl++) {
      int kA = ks * 64 + kl * 32 + fh * 8;
      v8bf a0 = ldsA256(As, wr + fl, kA);
      v8bf a1 = ldsA256(As, wr + 16 + fl, kA);
      int kb = kl * 64 + fh * 16;
      v8bf b0 = ldsB64(Bt, wc + fl, kb);
      v8bf b1 = ldsB64(Bt, wc + 16 + fl, kb);
      acc[0][0] = mfma16(a0, b0, acc[0][0]);
      acc[1][0] = mfma16(a1, b0, acc[1][0]);
      acc[0][1] = mfma16(a0, b1, acc[0][1]);
      acc[1][1] = mfma16(a1, b1, acc[1][1]);
    }
    if (ks == 3) {
      int nb = t >> 2, wsel = nb >> 1, c0 = (nb & 1) * 128;
      u16* out = (u16*)qkv + (size_t)wsel * qkvZ;
      #pragma unroll
      for (int nj = 0; nj < 2; nj++) {
        const int col = c0 + wc + nj * 16 + fl;
        const float bb = biasp[wsel * 256 + col];
        #pragma unroll
        for (int mi = 0; mi < 2; mi++)
          #pragma unroll
          for (int r2 = 0; r2 < 4; r2++) {
            int row = m0 + wr + mi * 16 + fh * 4 + r2;
            out[(size_t)row * 256 + col] = f2b(acc[mi][nj][r2] + bb);
          }
      }
      #pragma unroll
      for (int i = 0; i < 2; i++)
        #pragma unroll
        for (int j = 0; j < 2; j++) { v4f z = {0.f,0.f,0.f,0.f}; acc[i][j] = z; }
    }
  }
}

// ---------------------------------------------------------------------------
// O-projection: x += o @ WoT + bo. A (o tile) staged via pre-swizzled-source
// global_load_lds; Wo pipelined as 8 [256][32] tiles through the double
// buffer. Full 64x256 C per block (2m x 4n waves), 8 MFMA/wave per step.
// ---------------------------------------------------------------------------
__global__ __launch_bounds__(512, 4)
void oproj(const bf16* __restrict__ op, const bf16* __restrict__ wop,
           const float* __restrict__ bop, float* __restrict__ xp)
{
  __shared__ __align__(16) u16 As[64 * 256];   // 32 KB
  __shared__ __align__(16) u16 Bs[2 * 8192];   // 32 KB
  const int tid = threadIdx.x;
  const int w = tid >> 6, lane = tid & 63;
  const int m0 = blockIdx.x * 64;
  const u16* og = (const u16*)op + (size_t)m0 * 256;
  #pragma unroll
  for (int i = 0; i < 4; i++) {
    int b = i * 8192 + tid * 16;                 // linear LDS byte
    int row = b >> 9, cb = b & 511;
    int srce = (row << 8) + ((cb ^ ((row & 7) << 4)) >> 1);  // u16 elems
    async16(og + srce, As + (b >> 1));
  }
  int so[2];
  so_256x32(tid, 256, so);
  const u16* wo16 = (const u16*)wop;
  stage_tile(wo16, so, Bs, 0, tid);
  const int wr = (w >> 2) * 32;
  const int wc = (w & 3) * 64;
  const int fl = lane & 15, fh = lane >> 4;
  v4f acc[2][4];
  #pragma unroll
  for (int i = 0; i < 2; i++)
    #pragma unroll
    for (int j = 0; j < 4; j++) { v4f z = {0.f,0.f,0.f,0.f}; acc[i][j] = z; }
  #pragma unroll 1
  for (int t = 0; t < 8; t++) {
    __syncthreads();
    if (t + 1 < 8)
      stage_tile(wo16 + (t + 1) * 32, so, Bs, ((t + 1) & 1) * 8192, tid);
    const u16* Bt = Bs + (t & 1) * 8192;
    int kA = t * 32 + fh * 8;
    v8bf a0 = ldsA256(As, wr + fl, kA);
    v8bf a1 = ldsA256(As, wr + 16 + fl, kA);
    int kb = fh * 16;
    #pragma unroll
    for (int nj = 0; nj < 4; nj++) {
      v8bf b = ldsB32(Bt, wc + nj * 16 + fl, kb);
      acc[0][nj] = mfma16(a0, b, acc[0][nj]);
      acc[1][nj] = mfma16(a1, b, acc[1][nj]);
    }
  }
  #pragma unroll
  for (int nj = 0; nj < 4; nj++) {
    const int col = wc + nj * 16 + fl;
    const float bb = bop[col];
    #pragma unroll
    for (int mi = 0; mi < 2; mi++)
      #pragma unroll
      for (int r2 = 0; r2 < 4; r2++) {
        size_t idx = (size_t)(m0 + wr + mi * 16 + fh * 4 + r2) * 256 + col;
        xp[idx] += acc[mi][nj][r2] + bb;
      }
  }
}

// ---------------------------------------------------------------------------
// Fused FFN: x += relu(LN2(x) @ W1 + b1) @ W2 + b2.  64-row tile, 8 waves.
// LN'd A staged once (32 KB). 64-tile pipeline: per 128-col hidden chunk nc,
// 4 W1 tiles [128][64] then 4 W2 tiles [256][32] flow through the 32 KB
// double buffer; f-chunk lives in regs -> ReLU -> swizzled Fs -> W2 MFMAs
// accumulate into persistent 64x256 C. f never touches HBM.
// ---------------------------------------------------------------------------
__global__ __launch_bounds__(512, 4)
void ffn_fused(float* __restrict__ xp, const float* __restrict__ gp,
               const float* __restrict__ bp, const bf16* __restrict__ w1p,
               const bf16* __restrict__ w2p, const float* __restrict__ b1p,
               const float* __restrict__ b2p)
{
  __shared__ __align__(16) u16 As[64 * 256];   // 32 KB
  __shared__ __align__(16) u16 Fs[64 * 128];   // 16 KB
  __shared__ __align__(16) u16 Bs[2 * 8192];   // 32 KB
  const int tid = threadIdx.x;
  const int w = tid >> 6, lane = tid & 63;
  const int m0 = blockIdx.x * 64;
  int so1[2], so2[2];
  so_128x64(tid, so1);
  so_256x32(tid, 1024, so2);
  const u16* w1 = (const u16*)w1p;
  const u16* w2 = (const u16*)w2p;
  stage_tile(w1, so1, Bs, 0, tid);    // tile 0: nc=0 W1 ks=0
  ln_stage(xp, gp, bp, As, m0, w, lane);
  const int wr = (w >> 2) * 32;
  const int wc = (w & 3) * 32;       // W1 col-group (128 cols)
  const int wc2 = (w & 3) * 64;      // W2 col-group (256 cols)
  const int fl = lane & 15, fh = lane >> 4;
  v4f acc[2][4];
  v4f fa[2][2];
  #pragma unroll
  for (int i = 0; i < 2; i++) {
    #pragma unroll
    for (int j = 0; j < 4; j++) { v4f z = {0.f,0.f,0.f,0.f}; acc[i][j] = z; }
    #pragma unroll
    for (int j = 0; j < 2; j++) { v4f z = {0.f,0.f,0.f,0.f}; fa[i][j] = z; }
  }
  #pragma unroll 1
  for (int t = 0; t < 64; t++) {
    __syncthreads();
    if (t + 1 < 64) {
      int t1 = t + 1, nc1 = t1 >> 3, sub1 = t1 & 7;
      int bufo = ((t + 1) & 1) * 8192;
      if (sub1 < 4)
        stage_tile(w1 + nc1 * 32768 + sub1 * 64, so1, Bs, bufo, tid);
      else
        stage_tile(w2 + nc1 * 128 + (sub1 - 4) * 32, so2, Bs, bufo, tid);
    }
    const u16* Bt = Bs + (t & 1) * 8192;
    const int sub = t & 7;
    if (sub < 4) {
      // ---- W1 step: fa += A[:, sub*64..] @ B1tile ----
      #pragma unroll
      for (int kl = 0; kl < 2; kl++) {
        int kA = sub * 64 + kl * 32 + fh * 8;
        v8bf a0 = ldsA256(As, wr + fl, kA);
        v8bf a1 = ldsA256(As, wr + 16 + fl, kA);
        int kb = kl * 64 + fh * 16;
        v8bf b0 = ldsB64(Bt, wc + fl, kb);
        v8bf b1 = ldsB64(Bt, wc + 16 + fl, kb);
        fa[0][0] = mfma16(a0, b0, fa[0][0]);
        fa[1][0] = mfma16(a1, b0, fa[1][0]);
        fa[0][1] = mfma16(a0, b1, fa[0][1]);
        fa[1][1] = mfma16(a1, b1, fa[1][1]);
      }
      if (sub == 3) {
        // bias + relu -> swizzled Fs; rezero fa
        int nc = t >> 3;
        #pragma unroll
        for (int nj = 0; nj < 2; nj++) {
          const int colc = wc + nj * 16 + fl;
          const float bb = b1p[nc * 128 + colc];
          #pragma unroll
          for (int mi = 0; mi < 2; mi++)
            #pragma unroll
            for (int r2 = 0; r2 < 4; r2++) {
              int row = wr + mi * 16 + fh * 4 + r2;
              float vv = fmaxf(fa[mi][nj][r2] + bb, 0.f);
              int byte = (row << 8) + (((colc << 1) & 255) ^ ((row & 7) << 4));
              *(u16*)((char*)Fs + byte) = f2b(vv);
            }
        }
        #pragma unroll
        for (int i = 0; i < 2; i++)
          #pragma unroll
          for (int j = 0; j < 2; j++) { v4f z = {0.f,0.f,0.f,0.f}; fa[i][j] = z; }
      }
    } else {
      // ---- W2 step: acc += Fs[:, ks*32..] @ B2tile ----
      int ks = sub - 4;
      int kA = ks * 32 + fh * 8;
      v8bf a0 = ldsA128(Fs, wr + fl, kA);
      v8bf a1 = ldsA128(Fs, wr + 16 + fl, kA);
      int kb = fh * 16;
      #pragma unroll
      for (int nj = 0; nj < 4; nj++) {
        v8bf b = ldsB32(Bt, wc2 + nj * 16 + fl, kb);
        acc[0][nj] = mfma16(a0, b, acc[0][nj]);
        acc[1][nj] = mfma16(a1, b, acc[1][nj]);
      }
    }
  }
  // epilogue: + b2 + residual, write x (f32)
  #pragma unroll
  for (int nj = 0; nj < 4; nj++) {
    const int col = wc2 + nj * 16 + fl;
    const float bb = b2p[col];
    #pragma unroll
    for (int mi = 0; mi < 2; mi++)
      #pragma unroll
      for (int r2 = 0; r2 < 4; r2++) {
        size_t idx = (size_t)(m0 + wr + mi * 16 + fh * 4 + r2) * 256 + col;
        xp[idx] += acc[mi][nj][r2] + bb;
      }
  }
}

// ---------------------------------------------------------------------------
// Attention: seq_len 3, H=8, DH=32, bf16 in/out. 8 sequences per block.
// ---------------------------------------------------------------------------
__global__ __launch_bounds__(256)
void attn(const bf16* __restrict__ qp, const bf16* __restrict__ kp,
          const bf16* __restrict__ vp, bf16* __restrict__ op)
{
  __shared__ __align__(16) u16 qs[6144], ks[6144], vs[6144];
  __shared__ float probs[8][8][9];
  const int tid = threadIdx.x;
  const size_t gbase = (size_t)blockIdx.x * 6144;   // 8 seq * 3 tok * 256
  const uint4* qg = (const uint4*)((const u16*)qp + gbase);
  const uint4* kg = (const uint4*)((const u16*)kp + gbase);
  const uint4* vg = (const uint4*)((const u16*)vp + gbase);
  for (int c = tid; c < 768; c += 256) {
    ((uint4*)qs)[c] = qg[c];
    ((uint4*)ks)[c] = kg[c];
    ((uint4*)vs)[c] = vg[c];
  }
  __syncthreads();
  if (tid < 64) {
    int s = tid >> 3, h = tid & 7;
    int base = s * 768 + h * 32;
    float sc[3][3];
    #pragma unroll
    for (int i = 0; i < 3; i++)
      #pragma unroll
      for (int j = 0; j < 3; j++) {
        float sum = 0.f;
        #pragma unroll
        for (int d = 0; d < 32; d++)
          sum += b2f(qs[base + i * 256 + d]) * b2f(ks[base + j * 256 + d]);
        sc[i][j] = sum * 0.17677669529663687f;   // DH^-0.5
      }
    #pragma unroll
    for (int i = 0; i < 3; i++) {
      float m = fmaxf(sc[i][0], fmaxf(sc[i][1], sc[i][2]));
      float e0 = __expf(sc[i][0] - m);
      float e1 = __expf(sc[i][1] - m);
      float e2 = __expf(sc[i][2] - m);
      float inv = 1.f / (e0 + e1 + e2);
      probs[s][h][i * 3 + 0] = e0 * inv;
      probs[s][h][i * 3 + 1] = e1 * inv;
      probs[s][h][i * 3 + 2] = e2 * inv;
    }
  }
  __syncthreads();
  u16* og = (u16*)op + gbase;
  for (int c = tid; c < 6144; c += 256) {
    int lrow = c >> 8, hd = c & 255;
    int s = lrow / 3, i = lrow - s * 3;
    int h = hd >> 5;
    float p0 = probs[s][h][i * 3 + 0];
    float p1 = probs[s][h][i * 3 + 1];
    float p2 = probs[s][h][i * 3 + 2];
    float o = p0 * b2f(vs[s * 768 + hd])
            + p1 * b2f(vs[s * 768 + 256 + hd])
            + p2 * b2f(vs[s * 768 + 512 + hd]);
    og[c] = f2b(o);
  }
}

// ---------------------------------------------------------------------------
// Final LN + mean over 3 tokens (f32 in, f32 out). 1 wave/seq, 4 seq/block.
// ---------------------------------------------------------------------------
__global__ __launch_bounds__(256)
void ln_final_mean(const float* __restrict__ xp, const float* __restrict__ gp,
                   const float* __restrict__ bp, float* __restrict__ outp)
{
  const int lane = threadIdx.x & 63;
  const int n = blockIdx.x * 4 + (threadIdx.x >> 6);
  float4 gv = *(const float4*)(gp + lane * 4);
  float4 bv4 = *(const float4*)(bp + lane * 4);
  float a0 = 0.f, a1 = 0.f, a2 = 0.f, a3 = 0.f;
  for (int t = 0; t < 3; t++) {
    float4 rv = *(const float4*)(xp + ((size_t)n * 3 + t) * 256 + lane * 4);
    float v0 = rv.x, v1 = rv.y, v2 = rv.z, v3 = rv.w;
    float s = v0 + v1 + v2 + v3;
    float q = v0 * v0 + v1 * v1 + v2 * v2 + v3 * v3;
    #pragma unroll
    for (int m = 32; m > 0; m >>= 1) {
      s += __shfl_xor(s, m, 64);
      q += __shfl_xor(q, m, 64);
    }
    float mean = s * (1.f / 256.f);
    float var = q * (1.f / 256.f) - mean * mean;
    float r = rsqrtf(var + 1e-5f);
    a0 += (v0 - mean) * r * gv.x + bv4.x;
    a1 += (v1 - mean) * r * gv.y + bv4.y;
    a2 += (v2 - mean) * r * gv.z + bv4.z;
    a3 += (v3 - mean) * r * gv.w + bv4.w;
  }
  const float third = 1.f / 3.f;
  float4 outv;
  outv.x = a0 * third;
  outv.y = a1 * third;
  outv.z = a2 * third;
  outv.w = a3 * third;
  *(float4*)(outp + (size_t)n * 256 + lane * 4) = outv;
}

// ---------------------------------------------------------------------------
extern "C" void kernel_launch(void* const* d_in, const int* in_sizes, int n_in,
                              void* d_out, int out_size, void* d_ws, size_t ws_size,
                              hipStream_t stream)
{
  const float* term = (const float*)d_in[0];
  const float* pred = (const float*)d_in[1];
  const float* Wq  = (const float*)d_in[2];
  const float* Wk  = (const float*)d_in[3];
  const float* Wv  = (const float*)d_in[4];
  const float* Wo  = (const float*)d_in[5];
  const float* bq  = (const float*)d_in[6];
  const float* bk  = (const float*)d_in[7];
  const float* bvv = (const float*)d_in[8];
  const float* bo  = (const float*)d_in[9];
  const float* ln1g = (const float*)d_in[10];
  const float* ln1b = (const float*)d_in[11];
  const float* ln2g = (const float*)d_in[12];
  const float* ln2b = (const float*)d_in[13];
  const float* W1  = (const float*)d_in[14];
  const float* b1  = (const float*)d_in[15];
  const float* W2  = (const float*)d_in[16];
  const float* b2  = (const float*)d_in[17];
  const float* lnfg = (const float*)d_in[18];
  const float* lnfb = (const float*)d_in[19];

  // Chunk count from ws_size. Per row: x f32 (1024 B) + q,k,v,o bf16 (2048 B).
  int nch = 128;
  for (int c = 2; c <= 128; c *= 2) {
    size_t Mc_ = (size_t)MROWS / c;
    size_t need = 4ull * 1024 * 1024 + Mc_ * 3072ull;
    if (need <= ws_size) { nch = c; break; }
  }
  const size_t Mc = (size_t)MROWS / nch;     // multiple of 1152

  char* ws = (char*)d_ws;
  bf16* wt   = (bf16*)ws;                    // 1572864 el (3 MB)
  float* bqkv = (float*)(ws + 3145728);      // 1536 f32
  float* x = (float*)(ws + 4194304);         // Mc*256 f32
  bf16* q = (bf16*)(x + Mc * 256);           // q,k,v,o contiguous bf16
  bf16* v_ = q + 2 * Mc * 256;
  bf16* o = q + 3 * Mc * 256;

  prep_weights<<<6145, 256, 0, stream>>>(Wq, Wk, Wv, Wo, W1, W2, bq, bk, bvv, wt, bqkv);

  const long long qkvZ = (long long)(Mc * 256);
  for (int ch = 0; ch < nch; ch++) {
    const int row0 = (int)(ch * Mc);
    build_x<<<(int)(Mc / 4), 256, 0, stream>>>(term, pred, x, row0);
    for (int l = 0; l < 2; l++) {
      const bf16* wl = wt + (size_t)l * 786432;
      qkv_fused<<<(int)(Mc / 64), 512, 0, stream>>>(
          x, ln1g + l * 256, ln1b + l * 256, wl, bqkv + l * 768, q, qkvZ);
      attn<<<(int)(Mc / 24), 256, 0, stream>>>(q, q + Mc * 256, v_, o);
      oproj<<<(int)(Mc / 64), 512, 0, stream>>>(o, wl + 196608, bo + l * 256, x);
      ffn_fused<<<(int)(Mc / 64), 512, 0, stream>>>(
          x, ln2g + l * 256, ln2b + l * 256, wl + 262144, wl + 524288,
          b1 + l * 1024, b2 + l * 256);
    }
    ln_final_mean<<<(int)(Mc / 12), 256, 0, stream>>>(
        x, lnfg, lnfb, (float*)d_out + (size_t)(row0 / 3) * 256);
  }
}

// Round 3
// 1533.189 us; speedup vs baseline: 1.8944x; 1.0116x over previous
//
#include <hip/hip_runtime.h>
#include <hip/hip_bf16.h>
#include <stdint.h>

typedef __hip_bfloat16 bf16;
typedef unsigned short u16;
typedef unsigned int u32;
typedef __bf16 v8bf __attribute__((ext_vector_type(8)));
typedef float v4f __attribute__((ext_vector_type(4)));

// Problem constants
#define NB 16384            // B
#define MROWS 147456        // T*B*3 token rows

__device__ __forceinline__ float b2f(u16 u) {
  union { u32 u; float f; } v; v.u = ((u32)u) << 16; return v.f;
}
__device__ __forceinline__ u16 f2b(float f) {
  union { float f; u32 u; } v; v.f = f;
  u32 u = v.u;
  return (u16)((u + 0x7fffu + ((u >> 16) & 1u)) >> 16);
}
__device__ __forceinline__ void async16(const u16* g, u16* lds) {
  __builtin_amdgcn_global_load_lds((const __attribute__((address_space(1))) void*)g,
                                   (__attribute__((address_space(3))) void*)lds,
                                   16, 0, 0);
}
__device__ __forceinline__ v4f mfma16(v8bf a, v8bf b, v4f c) {
  return __builtin_amdgcn_mfma_f32_16x16x32_bf16(a, b, c, 0, 0, 0);
}

// ---- swizzled LDS reads -----------------------------------------------------
// As/Fs: [rows][256] bf16 (512 B rows), XOR (row&7)<<4 -> conflict-free b128.
__device__ __forceinline__ v8bf ldsA256(const u16* As, int row, int k) {
  int byte = (row << 9) + ((k << 1) ^ ((row & 7) << 4));
  return *(const v8bf*)((const char*)As + byte);
}
// B tile [256 rows][64 k] (128 B rows), XOR (row&7)<<4; kb = in-row byte
__device__ __forceinline__ v8bf ldsB64(const u16* Bs, int row, int kb) {
  int byte = (row << 7) + (kb ^ ((row & 7) << 4));
  return *(const v8bf*)((const char*)Bs + byte);
}

// ---- B-tile staging: [256 rows][64 k] = 32 KB tile via global_load_lds.
// Linear LDS dest (wave-uniform base + lane*16), pre-swizzled global source.
// S = global row stride in elements. 4x async16 per thread (512 threads).
__device__ __forceinline__ void so4_init(int tid, int S, int* so) {
  #pragma unroll
  for (int i = 0; i < 4; i++) {
    int b = (tid + i * 512) * 16;        // linear LDS byte
    int r = b >> 7, ib = b & 127;
    so[i] = r * S + ((ib ^ ((r & 7) << 4)) >> 1);
  }
}
__device__ __forceinline__ void stage4(const u16* g, const int* so, u16* Bs, int tid) {
  #pragma unroll
  for (int i = 0; i < 4; i++)
    async16(g + so[i], Bs + tid * 8 + i * 4096);
}

// ---------------------------------------------------------------------------
// Weight prep (unchanged): transposed bf16 [N][K] per-layer layout in wt:
// q 0, k 65536, v 131072, o 196608, W1T 262144 (1024x256),
// W2T 524288 (256x1024); layer stride 786432 elements. bqkv: [l][qkv][256] f32.
// ---------------------------------------------------------------------------
__global__ __launch_bounds__(256)
void prep_weights(const float* Wq, const float* Wk, const float* Wv, const float* Wo,
                  const float* W1, const float* W2,
                  const float* bq, const float* bk, const float* bv,
                  bf16* wt, float* bqkv)
{
  if (blockIdx.x == 6144) {   // bias-pack block
    for (int e = threadIdx.x; e < 1536; e += 256) {
      int l = e / 768;
      int rem = e - l * 768;
      int wsel = rem >> 8;
      int col = rem & 255;
      const float* s = (wsel == 0) ? bq : (wsel == 1) ? bk : bv;
      bqkv[e] = s[l * 256 + col];
    }
    return;
  }
  int gid = blockIdx.x * 256 + threadIdx.x;   // [0, 1572864)
  int layer = (gid >= 786432) ? 1 : 0;
  int r = gid - layer * 786432;
  const float* src; int K, N, e, outoff;
  if (r < 262144) {
    int which = r >> 16;
    e = r & 65535; K = 256; N = 256;
    const float* w = (which == 0) ? Wq : (which == 1) ? Wk : (which == 2) ? Wv : Wo;
    src = w + layer * 65536;
    outoff = layer * 786432 + which * 65536;
  } else if (r < 524288) {
    e = r - 262144; K = 256; N = 1024;
    src = W1 + layer * 262144;
    outoff = layer * 786432 + 262144;
  } else {
    e = r - 524288; K = 1024; N = 256;
    src = W2 + layer * 262144;
    outoff = layer * 786432 + 524288;
  }
  int n = e / K, kk = e - n * K;
  ((u16*)wt)[outoff + e] = f2b(src[kk * N + n]);
}

// ---------------------------------------------------------------------------
// Graph-message build: write x rows (f32). 1 wave per row, 4 rows per block.
// ---------------------------------------------------------------------------
__global__ __launch_bounds__(256)
void build_x(const float* __restrict__ T, const float* __restrict__ P,
             float* __restrict__ X, int row0)
{
  const int lane = threadIdx.x & 63;
  const int lrow = blockIdx.x * 4 + (threadIdx.x >> 6);
  const int row = row0 + lrow;
  const int d0 = lane * 4;
  int n = row / 3;
  int t = row - n * 3;
  float4 v;
  if (t == 2) {
    v = *(const float4*)(T + (size_t)n * 256 + d0);
  } else {
    int tm = n >> 14, b = n & 16383;
    const int srcT[6] = {1, 2,  0, 2,  1, 0};
    const int srcP[6] = {0, 2,  0, 1,  1, 2};
    const float sg[6] = {-1.f, -1.f,  1.f, -1.f,  1.f, 1.f};
    int idx = tm * 2 + t;
    float4 tv = *(const float4*)(T + ((size_t)(srcT[idx] * NB + b)) * 256 + d0);
    float4 pv = *(const float4*)(P + ((size_t)(srcP[idx] * NB + b)) * 256 + d0);
    float s = sg[idx];
    v.x = tv.x + s * pv.x;
    v.y = tv.y + s * pv.y;
    v.z = tv.z + s * pv.z;
    v.w = tv.w + s * pv.w;
  }
  *(float4*)(X + (size_t)lrow * 256 + d0) = v;
}

// ---------------------------------------------------------------------------
// LN stage: read 64 rows of x (f32), LayerNorm, write bf16 into swizzled LDS
// tile As[64][256]. Wave w handles rows {w, w+8, ..., w+56}.
// ---------------------------------------------------------------------------
__device__ __forceinline__ void ln_stage(const float* __restrict__ xp,
                                         const float* __restrict__ gp,
                                         const float* __restrict__ bp,
                                         u16* As, int m0, int w, int lane)
{
  const float4 gv = *(const float4*)(gp + lane * 4);
  const float4 bv = *(const float4*)(bp + lane * 4);
  for (int r = w; r < 64; r += 8) {
    float4 v = *(const float4*)(xp + (size_t)(m0 + r) * 256 + lane * 4);
    float s = v.x + v.y + v.z + v.w;
    float q = v.x * v.x + v.y * v.y + v.z * v.z + v.w * v.w;
    #pragma unroll
    for (int m = 32; m > 0; m >>= 1) {
      s += __shfl_xor(s, m, 64);
      q += __shfl_xor(q, m, 64);
    }
    float mean = s * (1.f / 256.f);
    float var = q * (1.f / 256.f) - mean * mean;
    float rr = rsqrtf(var + 1e-5f);
    ushort4 o;
    o.x = f2b((v.x - mean) * rr * gv.x + bv.x);
    o.y = f2b((v.y - mean) * rr * gv.y + bv.y);
    o.z = f2b((v.z - mean) * rr * gv.z + bv.z);
    o.w = f2b((v.w - mean) * rr * gv.w + bv.w);
    int byte = (r << 9) + ((lane << 3) ^ ((r & 7) << 4));
    *(ushort4*)((char*)As + byte) = o;
  }
}

// ---- load full 64x256 A-tile as MFMA A-frags into registers (128 VGPR) ----
#define LOAD_AREGS(a, Src, fl, fh)                                  \
  _Pragma("unroll")                                                 \
  for (int mi = 0; mi < 4; mi++)                                    \
    _Pragma("unroll")                                               \
    for (int ks = 0; ks < 8; ks++)                                  \
      a[mi][ks] = ldsA256(Src, mi * 16 + fl, ks * 32 + fh * 8);

// ---------------------------------------------------------------------------
// Fused LN1 + QKV projection. 64-row tile, 8 waves. A-frags in registers
// (whole 64x256 per wave); each wave owns a 32-col output strip. B pipelined
// as 12 [256][64] tiles (3 wsel x 4 k-steps) through a 64 KB double buffer.
// Per step per wave: 4 LDS B-reads feed 16 MFMAs.
// ---------------------------------------------------------------------------
__global__ __launch_bounds__(512, 2)
void qkv_fused(const float* __restrict__ xp, const float* __restrict__ gp,
               const float* __restrict__ bp, const bf16* __restrict__ wp,
               const float* __restrict__ biasp, bf16* __restrict__ qkv,
               long long qkvZ)
{
  __shared__ __align__(16) u16 As[64 * 256];      // 32 KB
  __shared__ __align__(16) u16 Bs[2 * 16384];     // 64 KB
  const int tid = threadIdx.x;
  const int w = tid >> 6, lane = tid & 63;
  const int m0 = blockIdx.x * 64;
  const int fl = lane & 15, fh = lane >> 4;
  const int wc = w * 32;
  int so[4];
  so4_init(tid, 256, so);
  const u16* wp16 = (const u16*)wp;
  stage4(wp16, so, Bs, tid);                      // tile 0: wsel 0, kt 0
  ln_stage(xp, gp, bp, As, m0, w, lane);
  __syncthreads();
  v8bf a[4][8];
  LOAD_AREGS(a, As, fl, fh);
  #pragma unroll
  for (int wsel = 0; wsel < 3; wsel++) {
    v4f acc[4][2];
    #pragma unroll
    for (int mi = 0; mi < 4; mi++)
      #pragma unroll
      for (int nj = 0; nj < 2; nj++) { v4f z = {0.f,0.f,0.f,0.f}; acc[mi][nj] = z; }
    #pragma unroll
    for (int kt = 0; kt < 4; kt++) {
      const int t = wsel * 4 + kt;
      if (t + 1 < 12) {
        const int t1 = t + 1, ws1 = t1 >> 2, kt1 = t1 & 3;
        stage4(wp16 + ws1 * 65536 + kt1 * 64, so, Bs + (t1 & 1) * 16384, tid);
      }
      const u16* Bt = Bs + (t & 1) * 16384;
      #pragma unroll
      for (int kl = 0; kl < 2; kl++) {
        const int ksub = kt * 2 + kl;
        v8bf b0 = ldsB64(Bt, wc + fl, kl * 64 + fh * 16);
        v8bf b1 = ldsB64(Bt, wc + 16 + fl, kl * 64 + fh * 16);
        #pragma unroll
        for (int mi = 0; mi < 4; mi++) {
          acc[mi][0] = mfma16(a[mi][ksub], b0, acc[mi][0]);
          acc[mi][1] = mfma16(a[mi][ksub], b1, acc[mi][1]);
        }
      }
      __syncthreads();
    }
    u16* out = (u16*)qkv + (size_t)wsel * qkvZ;
    #pragma unroll
    for (int nj = 0; nj < 2; nj++) {
      const int col = wc + nj * 16 + fl;
      const float bb = biasp[wsel * 256 + col];
      #pragma unroll
      for (int mi = 0; mi < 4; mi++)
        #pragma unroll
        for (int r2 = 0; r2 < 4; r2++) {
          int row = m0 + mi * 16 + fh * 4 + r2;
          out[(size_t)row * 256 + col] = f2b(acc[mi][nj][r2] + bb);
        }
    }
  }
}

// ---------------------------------------------------------------------------
// O-projection: x += o @ WoT + bo. A (o tile) staged once via pre-swizzled
// source global_load_lds, then A-frags to registers. Wo pipelined as 4
// [256][64] tiles. Per step per wave: 4 B-reads, 16 MFMAs.
// ---------------------------------------------------------------------------
__global__ __launch_bounds__(512, 2)
void oproj(const bf16* __restrict__ op, const bf16* __restrict__ wop,
           const float* __restrict__ bop, float* __restrict__ xp)
{
  __shared__ __align__(16) u16 As[64 * 256];      // 32 KB
  __shared__ __align__(16) u16 Bs[2 * 16384];     // 64 KB
  const int tid = threadIdx.x;
  const int w = tid >> 6, lane = tid & 63;
  const int m0 = blockIdx.x * 64;
  const int fl = lane & 15, fh = lane >> 4;
  const int wc = w * 32;
  const u16* og = (const u16*)op + (size_t)m0 * 256;
  #pragma unroll
  for (int i = 0; i < 4; i++) {
    int b = i * 8192 + tid * 16;                  // linear LDS byte
    int row = b >> 9, cb = b & 511;
    int srce = row * 256 + ((cb ^ ((row & 7) << 4)) >> 1);
    async16(og + srce, As + (b >> 1));
  }
  int so[4];
  so4_init(tid, 256, so);
  const u16* wo16 = (const u16*)wop;
  stage4(wo16, so, Bs, tid);
  __syncthreads();
  v8bf a[4][8];
  LOAD_AREGS(a, As, fl, fh);
  v4f acc[4][2];
  #pragma unroll
  for (int mi = 0; mi < 4; mi++)
    #pragma unroll
    for (int nj = 0; nj < 2; nj++) { v4f z = {0.f,0.f,0.f,0.f}; acc[mi][nj] = z; }
  #pragma unroll
  for (int kt = 0; kt < 4; kt++) {
    if (kt + 1 < 4)
      stage4(wo16 + (kt + 1) * 64, so, Bs + ((kt + 1) & 1) * 16384, tid);
    const u16* Bt = Bs + (kt & 1) * 16384;
    #pragma unroll
    for (int kl = 0; kl < 2; kl++) {
      const int ksub = kt * 2 + kl;
      v8bf b0 = ldsB64(Bt, wc + fl, kl * 64 + fh * 16);
      v8bf b1 = ldsB64(Bt, wc + 16 + fl, kl * 64 + fh * 16);
      #pragma unroll
      for (int mi = 0; mi < 4; mi++) {
        acc[mi][0] = mfma16(a[mi][ksub], b0, acc[mi][0]);
        acc[mi][1] = mfma16(a[mi][ksub], b1, acc[mi][1]);
      }
    }
    __syncthreads();
  }
  #pragma unroll
  for (int nj = 0; nj < 2; nj++) {
    const int col = wc + nj * 16 + fl;
    const float bb = bop[col];
    #pragma unroll
    for (int mi = 0; mi < 4; mi++)
      #pragma unroll
      for (int r2 = 0; r2 < 4; r2++) {
        size_t idx = (size_t)(m0 + mi * 16 + fh * 4 + r2) * 256 + col;
        xp[idx] += acc[mi][nj][r2] + bb;
      }
  }
}

// ---------------------------------------------------------------------------
// Fused FFN: x += relu(LN2(x) @ W1 + b1) @ W2 + b2.  64-row tile, 8 waves.
// LN'd A-frags in registers (whole 64x256 per wave). Hidden processed in 4
// chunks of 256 cols; per chunk: 4 W1 B-tile steps (fa in regs) -> bias+relu
// -> swizzled Fs (64x256) -> 4 W2 B-tile steps accumulating into persistent
// 64x256 C (each wave a 32-col strip). f never touches HBM.
// ---------------------------------------------------------------------------
__global__ __launch_bounds__(512, 2)
void ffn_fused(float* __restrict__ xp, const float* __restrict__ gp,
               const float* __restrict__ bp, const bf16* __restrict__ w1p,
               const bf16* __restrict__ w2p, const float* __restrict__ b1p,
               const float* __restrict__ b2p)
{
  __shared__ __align__(16) u16 As[64 * 256];      // 32 KB
  __shared__ __align__(16) u16 Fs[64 * 256];      // 32 KB
  __shared__ __align__(16) u16 Bs[2 * 16384];     // 64 KB
  const int tid = threadIdx.x;
  const int w = tid >> 6, lane = tid & 63;
  const int m0 = blockIdx.x * 64;
  const int fl = lane & 15, fh = lane >> 4;
  const int wc = w * 32;
  int so1[4], so2[4];
  so4_init(tid, 256, so1);
  so4_init(tid, 1024, so2);
  const u16* w1 = (const u16*)w1p;
  const u16* w2 = (const u16*)w2p;
  stage4(w1, so1, Bs, tid);                       // t=0: nc 0, W1 ks 0
  ln_stage(xp, gp, bp, As, m0, w, lane);
  __syncthreads();
  v8bf a[4][8];
  LOAD_AREGS(a, As, fl, fh);
  v4f acc[4][2];
  #pragma unroll
  for (int mi = 0; mi < 4; mi++)
    #pragma unroll
    for (int nj = 0; nj < 2; nj++) { v4f z = {0.f,0.f,0.f,0.f}; acc[mi][nj] = z; }
  #pragma unroll
  for (int nc = 0; nc < 4; nc++) {
    v4f fa[4][2];
    #pragma unroll
    for (int mi = 0; mi < 4; mi++)
      #pragma unroll
      for (int nj = 0; nj < 2; nj++) { v4f z = {0.f,0.f,0.f,0.f}; fa[mi][nj] = z; }
    #pragma unroll
    for (int sub = 0; sub < 8; sub++) {
      const int t = nc * 8 + sub;
      if (t + 1 < 32) {
        const int t1 = t + 1, nc1 = t1 >> 3, sub1 = t1 & 7;
        u16* dst = Bs + (t1 & 1) * 16384;
        if (sub1 < 4) stage4(w1 + nc1 * 65536 + sub1 * 64, so1, dst, tid);
        else          stage4(w2 + nc1 * 256 + (sub1 - 4) * 64, so2, dst, tid);
      }
      const u16* Bt = Bs + (t & 1) * 16384;
      if (sub < 4) {
        // ---- W1 step: fa += A[:, sub*64..] @ W1tile ----
        #pragma unroll
        for (int kl = 0; kl < 2; kl++) {
          const int ksub = sub * 2 + kl;
          v8bf b0 = ldsB64(Bt, wc + fl, kl * 64 + fh * 16);
          v8bf b1 = ldsB64(Bt, wc + 16 + fl, kl * 64 + fh * 16);
          #pragma unroll
          for (int mi = 0; mi < 4; mi++) {
            fa[mi][0] = mfma16(a[mi][ksub], b0, fa[mi][0]);
            fa[mi][1] = mfma16(a[mi][ksub], b1, fa[mi][1]);
          }
        }
        if (sub == 3) {
          // bias + relu -> swizzled Fs
          #pragma unroll
          for (int nj = 0; nj < 2; nj++) {
            const int colc = wc + nj * 16 + fl;       // chunk-local col
            const float bb = b1p[nc * 256 + colc];
            #pragma unroll
            for (int mi = 0; mi < 4; mi++)
              #pragma unroll
              for (int r2 = 0; r2 < 4; r2++) {
                int row = mi * 16 + fh * 4 + r2;
                float vv = fmaxf(fa[mi][nj][r2] + bb, 0.f);
                int byte = (row << 9) + (((colc << 1)) ^ ((row & 7) << 4));
                *(u16*)((char*)Fs + byte) = f2b(vv);
              }
          }
        }
      } else {
        // ---- W2 step: acc += Fs[:, ks*64..] @ W2tile ----
        const int ks = sub - 4;
        #pragma unroll
        for (int kl = 0; kl < 2; kl++) {
          v8bf b0 = ldsB64(Bt, wc + fl, kl * 64 + fh * 16);
          v8bf b1 = ldsB64(Bt, wc + 16 + fl, kl * 64 + fh * 16);
          #pragma unroll
          for (int mi = 0; mi < 4; mi++) {
            v8bf af = ldsA256(Fs, mi * 16 + fl, (ks * 2 + kl) * 32 + fh * 8);
            acc[mi][0] = mfma16(af, b0, acc[mi][0]);
            acc[mi][1] = mfma16(af, b1, acc[mi][1]);
          }
        }
      }
      __syncthreads();
    }
  }
  // epilogue: + b2 + residual, write x (f32)
  #pragma unroll
  for (int nj = 0; nj < 2; nj++) {
    const int col = wc + nj * 16 + fl;
    const float bb = b2p[col];
    #pragma unroll
    for (int mi = 0; mi < 4; mi++)
      #pragma unroll
      for (int r2 = 0; r2 < 4; r2++) {
        size_t idx = (size_t)(m0 + mi * 16 + fh * 4 + r2) * 256 + col;
        xp[idx] += acc[mi][nj][r2] + bb;
      }
  }
}

// ---------------------------------------------------------------------------
// Attention: seq_len 3, H=8, DH=32, bf16 in/out. 8 sequences per block.
// ---------------------------------------------------------------------------
__global__ __launch_bounds__(256)
void attn(const bf16* __restrict__ qp, const bf16* __restrict__ kp,
          const bf16* __restrict__ vp, bf16* __restrict__ op)
{
  __shared__ __align__(16) u16 qs[6144], ks[6144], vs[6144];
  __shared__ float probs[8][8][9];
  const int tid = threadIdx.x;
  const size_t gbase = (size_t)blockIdx.x * 6144;   // 8 seq * 3 tok * 256
  const uint4* qg = (const uint4*)((const u16*)qp + gbase);
  const uint4* kg = (const uint4*)((const u16*)kp + gbase);
  const uint4* vg = (const uint4*)((const u16*)vp + gbase);
  for (int c = tid; c < 768; c += 256) {
    ((uint4*)qs)[c] = qg[c];
    ((uint4*)ks)[c] = kg[c];
    ((uint4*)vs)[c] = vg[c];
  }
  __syncthreads();
  if (tid < 64) {
    int s = tid >> 3, h = tid & 7;
    int base = s * 768 + h * 32;
    float sc[3][3];
    #pragma unroll
    for (int i = 0; i < 3; i++)
      #pragma unroll
      for (int j = 0; j < 3; j++) {
        float sum = 0.f;
        #pragma unroll
        for (int d = 0; d < 32; d++)
          sum += b2f(qs[base + i * 256 + d]) * b2f(ks[base + j * 256 + d]);
        sc[i][j] = sum * 0.17677669529663687f;   // DH^-0.5
      }
    #pragma unroll
    for (int i = 0; i < 3; i++) {
      float m = fmaxf(sc[i][0], fmaxf(sc[i][1], sc[i][2]));
      float e0 = __expf(sc[i][0] - m);
      float e1 = __expf(sc[i][1] - m);
      float e2 = __expf(sc[i][2] - m);
      float inv = 1.f / (e0 + e1 + e2);
      probs[s][h][i * 3 + 0] = e0 * inv;
      probs[s][h][i * 3 + 1] = e1 * inv;
      probs[s][h][i * 3 + 2] = e2 * inv;
    }
  }
  __syncthreads();
  u16* og = (u16*)op + gbase;
  for (int c = tid; c < 6144; c += 256) {
    int lrow = c >> 8, hd = c & 255;
    int s = lrow / 3, i = lrow - s * 3;
    int h = hd >> 5;
    float p0 = probs[s][h][i * 3 + 0];
    float p1 = probs[s][h][i * 3 + 1];
    float p2 = probs[s][h][i * 3 + 2];
    float o = p0 * b2f(vs[s * 768 + hd])
            + p1 * b2f(vs[s * 768 + 256 + hd])
            + p2 * b2f(vs[s * 768 + 512 + hd]);
    og[c] = f2b(o);
  }
}

// ---------------------------------------------------------------------------
// Final LN + mean over 3 tokens (f32 in, f32 out). 1 wave/seq, 4 seq/block.
// ---------------------------------------------------------------------------
__global__ __launch_bounds__(256)
void ln_final_mean(const float* __restrict__ xp, const float* __restrict__ gp,
                   const float* __restrict__ bp, float* __restrict__ outp)
{
  const int lane = threadIdx.x & 63;
  const int n = blockIdx.x * 4 + (threadIdx.x >> 6);
  float4 gv = *(const float4*)(gp + lane * 4);
  float4 bv4 = *(const float4*)(bp + lane * 4);
  float a0 = 0.f, a1 = 0.f, a2 = 0.f, a3 = 0.f;
  for (int t = 0; t < 3; t++) {
    float4 rv = *(const float4*)(xp + ((size_t)n * 3 + t) * 256 + lane * 4);
    float v0 = rv.x, v1 = rv.y, v2 = rv.z, v3 = rv.w;
    float s = v0 + v1 + v2 + v3;
    float q = v0 * v0 + v1 * v1 + v2 * v2 + v3 * v3;
    #pragma unroll
    for (int m = 32; m > 0; m >>= 1) {
      s += __shfl_xor(s, m, 64);
      q += __shfl_xor(q, m, 64);
    }
    float mean = s * (1.f / 256.f);
    float var = q * (1.f / 256.f) - mean * mean;
    float r = rsqrtf(var + 1e-5f);
    a0 += (v0 - mean) * r * gv.x + bv4.x;
    a1 += (v1 - mean) * r * gv.y + bv4.y;
    a2 += (v2 - mean) * r * gv.z + bv4.z;
    a3 += (v3 - mean) * r * gv.w + bv4.w;
  }
  const float third = 1.f / 3.f;
  float4 outv;
  outv.x = a0 * third;
  outv.y = a1 * third;
  outv.z = a2 * third;
  outv.w = a3 * third;
  *(float4*)(outp + (size_t)n * 256 + lane * 4) = outv;
}

// ---------------------------------------------------------------------------
extern "C" void kernel_launch(void* const* d_in, const int* in_sizes, int n_in,
                              void* d_out, int out_size, void* d_ws, size_t ws_size,
                              hipStream_t stream)
{
  const float* term = (const float*)d_in[0];
  const float* pred = (const float*)d_in[1];
  const float* Wq  = (const float*)d_in[2];
  const float* Wk  = (const float*)d_in[3];
  const float* Wv  = (const float*)d_in[4];
  const float* Wo  = (const float*)d_in[5];
  const float* bq  = (const float*)d_in[6];
  const float* bk  = (const float*)d_in[7];
  const float* bvv = (const float*)d_in[8];
  const float* bo  = (const float*)d_in[9];
  const float* ln1g = (const float*)d_in[10];
  const float* ln1b = (const float*)d_in[11];
  const float* ln2g = (const float*)d_in[12];
  const float* ln2b = (const float*)d_in[13];
  const float* W1  = (const float*)d_in[14];
  const float* b1  = (const float*)d_in[15];
  const float* W2  = (const float*)d_in[16];
  const float* b2  = (const float*)d_in[17];
  const float* lnfg = (const float*)d_in[18];
  const float* lnfb = (const float*)d_in[19];

  // Chunk count from ws_size. Per row: x f32 (1024 B) + q,k,v,o bf16 (2048 B).
  int nch = 128;
  for (int c = 2; c <= 128; c *= 2) {
    size_t Mc_ = (size_t)MROWS / c;
    size_t need = 4ull * 1024 * 1024 + Mc_ * 3072ull;
    if (need <= ws_size) { nch = c; break; }
  }
  const size_t Mc = (size_t)MROWS / nch;     // multiple of 1152

  char* ws = (char*)d_ws;
  bf16* wt   = (bf16*)ws;                    // 1572864 el (3 MB)
  float* bqkv = (float*)(ws + 3145728);      // 1536 f32
  float* x = (float*)(ws + 4194304);         // Mc*256 f32
  bf16* q = (bf16*)(x + Mc * 256);           // q,k,v,o contiguous bf16
  bf16* v_ = q + 2 * Mc * 256;
  bf16* o = q + 3 * Mc * 256;

  prep_weights<<<6145, 256, 0, stream>>>(Wq, Wk, Wv, Wo, W1, W2, bq, bk, bvv, wt, bqkv);

  const long long qkvZ = (long long)(Mc * 256);
  for (int ch = 0; ch < nch; ch++) {
    const int row0 = (int)(ch * Mc);
    build_x<<<(int)(Mc / 4), 256, 0, stream>>>(term, pred, x, row0);
    for (int l = 0; l < 2; l++) {
      const bf16* wl = wt + (size_t)l * 786432;
      qkv_fused<<<(int)(Mc / 64), 512, 0, stream>>>(
          x, ln1g + l * 256, ln1b + l * 256, wl, bqkv + l * 768, q, qkvZ);
      attn<<<(int)(Mc / 24), 256, 0, stream>>>(q, q + Mc * 256, v_, o);
      oproj<<<(int)(Mc / 64), 512, 0, stream>>>(o, wl + 196608, bo + l * 256, x);
      ffn_fused<<<(int)(Mc / 64), 512, 0, stream>>>(
          x, ln2g + l * 256, ln2b + l * 256, wl + 262144, wl + 524288,
          b1 + l * 1024, b2 + l * 256);
    }
    ln_final_mean<<<(int)(Mc / 12), 256, 0, stream>>>(
        x, lnfg, lnfb, (float*)d_out + (size_t)(row0 / 3) * 256);
  }
}